// Round 6
// baseline (191.125 us; speedup 1.0000x reference)
//
#include <hip/hip_runtime.h>

#define D_DIM 640
#define M_DIM 1024
#define B_DIM 32
#define BK 32
#define TILE 64
#define NT 10      // D/TILE
#define NPAIR 55   // NT*(NT+1)/2
#define OUT_ROW 205120  // 640*641/2

typedef __bf16 bf16x8 __attribute__((ext_vector_type(8)));
typedef float f32x16 __attribute__((ext_vector_type(16)));

__device__ __forceinline__ unsigned short f2bf(float f) {
    union { float f; unsigned int u; } c; c.f = f;
    unsigned int u = c.u;
    unsigned int r = (u + 0x7fffu + ((u >> 16) & 1u)) >> 16;
    return (unsigned short)r;
}

__device__ __forceinline__ float bf2f(unsigned short h) {
    union { unsigned int u; float f; } c; c.u = ((unsigned int)h) << 16;
    return c.f;
}

__device__ __forceinline__ void gload_lds16(const unsigned short* g, unsigned short* l) {
    __builtin_amdgcn_global_load_lds(
        (const __attribute__((address_space(1))) unsigned int*)g,
        (__attribute__((address_space(3))) unsigned int*)l,
        16, 0, 0);
}

__device__ __forceinline__ float block_reduce_256(float s) {
    #pragma unroll
    for (int off = 32; off > 0; off >>= 1) s += __shfl_down(s, off, 64);
    __shared__ float red[4];
    if ((threadIdx.x & 63) == 0) red[threadIdx.x >> 6] = s;
    __syncthreads();
    return red[0] + red[1] + red[2] + red[3];
}

// Kernel 1: fp32 -> bf16 cast + per-row sum of squares; zeroes accumulators.
__global__ void cast_diag_kernel(const float* __restrict__ x,
                                 unsigned short* __restrict__ xb,
                                 float* __restrict__ diag,
                                 float* __restrict__ rowsum,
                                 float* __restrict__ tot) {
    const size_t row = blockIdx.x;
    const int t = threadIdx.x;
    const float4 v = ((const float4*)(x + row * M_DIM))[t];
    float s = v.x * v.x + v.y * v.y + v.z * v.z + v.w * v.w;
    ushort4 o;
    o.x = f2bf(v.x); o.y = f2bf(v.y); o.z = f2bf(v.z); o.w = f2bf(v.w);
    ((ushort4*)(xb + row * M_DIM))[t] = o;
    float ssum = block_reduce_256(s);
    if (t == 0) { diag[row] = ssum; rowsum[row] = 0.f; }
    if (t == 1 && row < B_DIM) tot[row] = 0.f;
}

// Kernel 2: symmetric batched G = X X^T, 64x64 upper-tri tiles (it<=jt),
// mfma_32x32x16, fused dcov epilogue (bf16) + rowsum/tot atomics.
// R5 showed the 128-tile version latency-bound at 1.875 blocks/CU (MfmaUtil
// 9%, all pipes idle): with all blocks co-resident, kernel time = per-block
// K-loop latency. Fix = TLP: 1760 blocks, 32KB LDS -> 4 blocks/CU resident.
// 4-phase pipeline, depth 3; fenced asm vmcnt(N)+s_barrier (R4 lesson).
__global__ __launch_bounds__(256, 4)
void gemm_dcov_kernel(const unsigned short* __restrict__ xb,
                      const float* __restrict__ diag,
                      unsigned short* __restrict__ dcov,
                      float* __restrict__ rowsum,
                      float* __restrict__ tot) {
    // 4 phases x (A 2048 + B 2048 shorts) = 16384 shorts = 32 KB
    __shared__ __align__(16) unsigned short smem[16384];

    const int id = blockIdx.x;
    const int sub = id & 31;                 // 32 batches; id&7 -> XCD slot
    const int bt = (sub & 7) * 4 + (sub >> 3);
    int p = id >> 5;                          // 0..54 pair index
    int it = 0, off = p;
    while (off >= NT - it) { off -= NT - it; ++it; }
    const int jt = it + off;
    const bool diagTile = (it == jt);

    const int tid = threadIdx.x;
    const int w = tid >> 6, l = tid & 63;
    const int wy = w >> 1, wx = w & 1;
    const int lr = l & 31;    // A-row / B-col within 32-band
    const int lk = l >> 5;    // k-chunk selector (0..1)

    const unsigned short* gA = xb + ((size_t)bt * D_DIM + it * TILE) * M_DIM;
    const unsigned short* gB = xb + ((size_t)bt * D_DIM + jt * TILE) * M_DIM;

    // staging: thread t -> LDS offset t*16B (HW-fixed order). Global source
    // chunk picked so LDS chunk layout is XOR-swizzled: phys = c ^ ((r>>1)&3).
    const int cl = (((tid & 3) ^ ((tid >> 3) & 3)) << 3);
    const size_t aoff = (size_t)(tid >> 2) * M_DIM + cl;
    const int ldst = tid * 8;

    auto issue = [&](int k, int ph) {
        unsigned short* s = smem + ph * 4096;
        const int koff = k * BK;
        gload_lds16(gA + aoff + koff, s + ldst);          // A 64x32
        gload_lds16(gB + aoff + koff, s + 2048 + ldst);   // B 64x32
    };

    f32x16 acc;
    #pragma unroll
    for (int i = 0; i < 16; i++) acc[i] = 0.f;

    // fragment read offsets (shorts): row r=band+lr, mfma m chunk c=2m+lk,
    // phys chunk = c ^ ((lr>>1)&3)   [band*32 doesn't affect (r>>1)&3]
    const int swz = (lr >> 1) & 3;
    const int a0 = (wy * 32 + lr) * BK + (((lk) ^ swz) << 3);
    const int a1 = (wy * 32 + lr) * BK + (((2 + lk) ^ swz) << 3);
    const int b0 = 2048 + (wx * 32 + lr) * BK + (((lk) ^ swz) << 3);
    const int b1 = 2048 + (wx * 32 + lr) * BK + (((2 + lk) ^ swz) << 3);

    issue(0, 0); issue(1, 1); issue(2, 2);  // 6 loads in flight per wave

    int ph = 0;
    for (int k = 0; k < 32; ++k) {
        if (k < 30)       asm volatile("s_waitcnt vmcnt(4)" ::: "memory");
        else if (k == 30) asm volatile("s_waitcnt vmcnt(2)" ::: "memory");
        else              asm volatile("s_waitcnt vmcnt(0)" ::: "memory");
        asm volatile("s_barrier" ::: "memory");
        if (k < 29) issue(k + 3, (ph + 3) & 3);  // overwrites buffer read at k-1

        const unsigned short* s = smem + ph * 4096;
        bf16x8 fa0 = *(const bf16x8*)&s[a0];
        bf16x8 fb0 = *(const bf16x8*)&s[b0];
        bf16x8 fa1 = *(const bf16x8*)&s[a1];
        bf16x8 fb1 = *(const bf16x8*)&s[b1];
        acc = __builtin_amdgcn_mfma_f32_32x32x16_bf16(fa0, fb0, acc, 0, 0, 0);
        acc = __builtin_amdgcn_mfma_f32_32x32x16_bf16(fa1, fb1, acc, 0, 0, 0);

        ph = (ph + 1) & 3;
    }

    // stage diag slices into phase-0 area (last reads were phase 3 -> safe)
    float* sd = (float*)smem;
    if (tid < TILE)           sd[tid] = diag[(size_t)bt * D_DIM + it * TILE + tid];
    else if (tid < 2 * TILE)  sd[tid] = diag[(size_t)bt * D_DIM + jt * TILE + (tid - TILE)];
    __syncthreads();

    const float temp = 7.62939453125e-07f;  // 1/(2*640*1024)
    unsigned short* dbase = dcov + (size_t)bt * D_DIM * D_DIM;
    float* rs = rowsum + (size_t)bt * D_DIM;
    const int gcol = jt * TILE + wx * 32 + lr;
    const float dj = sd[TILE + wx * 32 + lr];
    float cp = 0.f;

    #pragma unroll
    for (int r = 0; r < 16; r++) {
        const int row_local = (r & 3) + 8 * (r >> 2) + 4 * lk;
        const int grow = it * TILE + wy * 32 + row_local;
        const float di = sd[wy * 32 + row_local];
        const float g = acc[r];
        const float v = sqrtf(fmaf(temp, fmaxf(di + dj - 2.f * g, 0.f), 1e-5f));
        dbase[(size_t)grow * D_DIM + gcol] = f2bf(v);
        cp += v;
        float rp = v;  // row sum over this wave's 32 cols (within 32-lane half)
        rp += __shfl_down(rp, 16, 32);
        rp += __shfl_down(rp, 8, 32);
        rp += __shfl_down(rp, 4, 32);
        rp += __shfl_down(rp, 2, 32);
        rp += __shfl_down(rp, 1, 32);
        if (lr == 0) atomicAdd(&rs[grow], rp);
    }
    float ts = cp;  // per-lane total of its 16 values
    if (!diagTile) {
        // mirrored tile (jt,it): its row sums == our column sums
        float c = cp + __shfl_down(cp, 32);
        if (l < 32) atomicAdd(&rs[gcol], c);
    }
    float bs = block_reduce_256(ts);
    if (tid == 0) atomicAdd(&tot[bt], diagTile ? bs : 2.f * bs);
}

// Kernel 3: double centering + triu gather (bf16 dcov read, fp32 out).
__global__ void output_kernel(const unsigned short* __restrict__ dcov,
                              const float* __restrict__ rowsum,
                              const float* __restrict__ tot,
                              float* __restrict__ out) {
    const int b = blockIdx.x / D_DIM;
    const int i = blockIdx.x - b * D_DIM;
    const float inv_d = 1.f / (float)D_DIM;
    const float rmi = rowsum[(size_t)b * D_DIM + i] * inv_d;
    const float tm = tot[b] * (inv_d * inv_d);
    const unsigned short* drow = dcov + ((size_t)b * D_DIM + i) * D_DIM;
    const float* rs = rowsum + (size_t)b * D_DIM;
    float* orow = out + (size_t)b * OUT_ROW + (size_t)i * D_DIM - (size_t)i * (i - 1) / 2;
    for (int j = i + threadIdx.x; j < D_DIM; j += 256)
        orow[j - i] = bf2f(drow[j]) - rmi - rs[j] * inv_d + tm;
}

extern "C" void kernel_launch(void* const* d_in, const int* in_sizes, int n_in,
                              void* d_out, int out_size, void* d_ws, size_t ws_size,
                              hipStream_t stream) {
    const float* x = (const float*)d_in[0];
    float* out = (float*)d_out;

    char* ws = (char*)d_ws;
    unsigned short* xb = (unsigned short*)ws;                 // 41,943,040 B
    size_t off = 41943040;
    float* diag = (float*)(ws + off);           off += 81920;
    unsigned short* dcov = (unsigned short*)(ws + off); off += 26214400;  // bf16
    float* rowsum = (float*)(ws + off);         off += 81920;
    float* tot = (float*)(ws + off);            off += 256;

    cast_diag_kernel<<<dim3(B_DIM * D_DIM), 256, 0, stream>>>(x, xb, diag, rowsum, tot);
    gemm_dcov_kernel<<<dim3(NPAIR * B_DIM), 256, 0, stream>>>(xb, diag, dcov, rowsum, tot);
    output_kernel<<<dim3(B_DIM * D_DIM), 256, 0, stream>>>(dcov, rowsum, tot, out);
}

// Round 7
// 171.778 us; speedup vs baseline: 1.1126x; 1.1126x over previous
//
#include <hip/hip_runtime.h>

#define D_DIM 640
#define M_DIM 1024
#define B_DIM 32
#define BK 32
#define OUT_ROW 205120  // 640*641/2

typedef __bf16 bf16x8 __attribute__((ext_vector_type(8)));
typedef float f32x4 __attribute__((ext_vector_type(4)));

__device__ __forceinline__ unsigned short f2bf(float f) {
    union { float f; unsigned int u; } c; c.f = f;
    unsigned int u = c.u;
    unsigned int r = (u + 0x7fffu + ((u >> 16) & 1u)) >> 16;
    return (unsigned short)r;
}

__device__ __forceinline__ float bf2f(unsigned short h) {
    union { unsigned int u; float f; } c; c.u = ((unsigned int)h) << 16;
    return c.f;
}

__device__ __forceinline__ void gload_lds16(const unsigned short* g, unsigned short* l) {
    __builtin_amdgcn_global_load_lds(
        (const __attribute__((address_space(1))) unsigned int*)g,
        (__attribute__((address_space(3))) unsigned int*)l,
        16, 0, 0);
}

__device__ __forceinline__ float block_reduce_256(float s) {
    #pragma unroll
    for (int off = 32; off > 0; off >>= 1) s += __shfl_down(s, off, 64);
    __shared__ float red[4];
    if ((threadIdx.x & 63) == 0) red[threadIdx.x >> 6] = s;
    __syncthreads();
    return red[0] + red[1] + red[2] + red[3];
}

// Kernel 1: fp32 -> bf16 cast + per-row sum of squares; zeroes accumulators.
__global__ void cast_diag_kernel(const float* __restrict__ x,
                                 unsigned short* __restrict__ xb,
                                 float* __restrict__ diag,
                                 float* __restrict__ rowsum,
                                 float* __restrict__ tot) {
    const size_t row = blockIdx.x;
    const int t = threadIdx.x;
    const float4 v = ((const float4*)(x + row * M_DIM))[t];
    float s = v.x * v.x + v.y * v.y + v.z * v.z + v.w * v.w;
    ushort4 o;
    o.x = f2bf(v.x); o.y = f2bf(v.y); o.z = f2bf(v.z); o.w = f2bf(v.w);
    ((ushort4*)(xb + row * M_DIM))[t] = o;
    float ssum = block_reduce_256(s);
    if (t == 0) { diag[row] = ssum; rowsum[row] = 0.f; }
    if (t == 1 && row < B_DIM) tot[row] = 0.f;
}

// Kernel 2: R4's exact gemm structure (the best measured: <49.3 us) with ONE
// change: dcov stored as bf16 (R5's output-kernel win). 128-tile, 16x16x32
// MFMA, 3 LDS phases (48 KB -> LDS allows 3 blocks/CU), two fenced barriers
// per K-iter, depth-3 prefetch with s_waitcnt vmcnt(8). R5's 4-phase/64KB
// variant regressed gemm 49->62 (residency 3->2 blocks/CU); R6's 64-tile TLP
// variant had 4cyc/read bank conflicts. This recombines the winners.
__global__ __launch_bounds__(256, 2)
void gemm_dcov_kernel(const unsigned short* __restrict__ xb,
                      const float* __restrict__ diag,
                      unsigned short* __restrict__ dcov,
                      float* __restrict__ rowsum,
                      float* __restrict__ tot) {
    // 3 phases x (A 4096 + B 4096 shorts) = 24576 shorts = 48 KB
    __shared__ __align__(16) unsigned short smem[24576];

    const int id = blockIdx.x;
    const int bt = (id & 7) * 4 + ((id >> 3) & 3);  // batch; tiles of a batch share an XCD
    int p = id >> 5;                                 // 0..14 tile-pair index
    int it = 0, off = p;
    while (off >= 5 - it) { off -= 5 - it; ++it; }
    const int jt = it + off;
    const bool diagTile = (it == jt);

    const int tid = threadIdx.x;
    const int w = tid >> 6, l = tid & 63;
    const int wy = w >> 1, wx = w & 1;
    const int lm = l & 15, quad = l >> 4;

    const unsigned short* gA = xb + ((size_t)bt * D_DIM + it * 128) * M_DIM;
    const unsigned short* gB = xb + ((size_t)bt * D_DIM + jt * 128) * M_DIM;

    // staging: lane writes LDS at tid*16B (fixed by global_load_lds); pick the
    // global source chunk so LDS gets XOR-swizzled (bank-conflict-free reads).
    const int r0 = tid >> 2;
    const int cl = (((tid & 3) ^ ((tid >> 3) & 3)) << 3);
    const size_t aoff1 = (size_t)r0 * M_DIM + cl;
    const size_t aoff2 = aoff1 + (size_t)64 * M_DIM;
    const int ldst = tid * 8;

    auto issue = [&](int k, int ph) {
        unsigned short* sA = smem + ph * 8192;
        unsigned short* sB = sA + 4096;
        const int koff = k * BK;
        gload_lds16(gA + aoff1 + koff, sA + ldst);
        gload_lds16(gA + aoff2 + koff, sA + ldst + 2048);
        gload_lds16(gB + aoff1 + koff, sB + ldst);
        gload_lds16(gB + aoff2 + koff, sB + ldst + 2048);
    };

    f32x4 acc[4][4];
    const f32x4 zero = {0.f, 0.f, 0.f, 0.f};
    #pragma unroll
    for (int i = 0; i < 4; i++)
        #pragma unroll
        for (int j = 0; j < 4; j++) acc[i][j] = zero;

    const int sw = ((quad ^ ((lm >> 1) & 3)) << 3);  // swizzled chunk offset

    issue(0, 0); issue(1, 1); issue(2, 2);  // 12 loads in flight per lane

    int ph = 0;
    for (int k = 0; k < 32; ++k) {
        // wait only for phase k's 4 loads; keep the rest in flight.
        if (k < 30)       asm volatile("s_waitcnt vmcnt(8)" ::: "memory");
        else if (k == 30) asm volatile("s_waitcnt vmcnt(4)" ::: "memory");
        else              asm volatile("s_waitcnt vmcnt(0)" ::: "memory");
        asm volatile("s_barrier" ::: "memory");

        const unsigned short* sA = smem + ph * 8192;
        const unsigned short* sB = sA + 4096;
        bf16x8 af[4], bfr[4];
        #pragma unroll
        for (int mi = 0; mi < 4; mi++)
            af[mi] = *(const bf16x8*)&sA[(wy * 64 + mi * 16 + lm) * BK + sw];
        #pragma unroll
        for (int ni = 0; ni < 4; ni++)
            bfr[ni] = *(const bf16x8*)&sB[(wx * 64 + ni * 16 + lm) * BK + sw];

        #pragma unroll
        for (int mi = 0; mi < 4; mi++)
            #pragma unroll
            for (int ni = 0; ni < 4; ni++)
                acc[mi][ni] = __builtin_amdgcn_mfma_f32_16x16x32_bf16(
                    af[mi], bfr[ni], acc[mi][ni], 0, 0, 0);

        asm volatile("s_barrier" ::: "memory");  // all waves done reading ph
        if (k + 3 < 32) issue(k + 3, ph);
        ph = (ph == 2) ? 0 : ph + 1;
    }

    // stage diag slices in LDS (reuse smem; safe after final barrier)
    float* sd = (float*)smem;
    if (tid < 128) sd[tid] = diag[(size_t)bt * D_DIM + it * 128 + tid];
    else           sd[tid] = diag[(size_t)bt * D_DIM + jt * 128 + (tid - 128)];
    __syncthreads();

    const float temp = 7.62939453125e-07f;  // 1/(2*640*1024)
    unsigned short* dbase = dcov + (size_t)bt * D_DIM * D_DIM;
    float* rs = rowsum + (size_t)bt * D_DIM;
    float ts = 0.f;
    float cp[4] = {0.f, 0.f, 0.f, 0.f};

    #pragma unroll
    for (int mi = 0; mi < 4; mi++) {
        #pragma unroll
        for (int r = 0; r < 4; r++) {
            const int lrow = wy * 64 + mi * 16 + quad * 4 + r;
            const int grow = it * 128 + lrow;
            const float di = sd[lrow];
            float rp = 0.f;
            #pragma unroll
            for (int ni = 0; ni < 4; ni++) {
                const int lcol = wx * 64 + ni * 16 + lm;
                const int gcol = jt * 128 + lcol;
                const float dj = sd[128 + lcol];
                const float g = acc[mi][ni][r];
                const float v = sqrtf(fmaf(temp, fmaxf(di + dj - 2.f * g, 0.f), 1e-5f));
                dbase[(size_t)grow * D_DIM + gcol] = f2bf(v);
                rp += v;
                cp[ni] += v;
            }
            ts += rp;
            rp += __shfl_down(rp, 8, 16);
            rp += __shfl_down(rp, 4, 16);
            rp += __shfl_down(rp, 2, 16);
            rp += __shfl_down(rp, 1, 16);
            if (lm == 0) atomicAdd(&rs[grow], rp);
        }
    }
    if (!diagTile) {
        // mirrored lower tile (jt,it): its row sums == our column sums
        #pragma unroll
        for (int ni = 0; ni < 4; ni++) {
            float c = cp[ni];
            c += __shfl_down(c, 32);
            c += __shfl_down(c, 16);
            if (l < 16) atomicAdd(&rs[jt * 128 + wx * 64 + ni * 16 + lm], c);
        }
    }
    float bs = block_reduce_256(ts);
    if (tid == 0) atomicAdd(&tot[bt], diagTile ? bs : 2.f * bs);
}

// Kernel 3: double centering + triu gather (bf16 dcov read, fp32 out).
__global__ void output_kernel(const unsigned short* __restrict__ dcov,
                              const float* __restrict__ rowsum,
                              const float* __restrict__ tot,
                              float* __restrict__ out) {
    const int b = blockIdx.x / D_DIM;
    const int i = blockIdx.x - b * D_DIM;
    const float inv_d = 1.f / (float)D_DIM;
    const float rmi = rowsum[(size_t)b * D_DIM + i] * inv_d;
    const float tm = tot[b] * (inv_d * inv_d);
    const unsigned short* drow = dcov + ((size_t)b * D_DIM + i) * D_DIM;
    const float* rs = rowsum + (size_t)b * D_DIM;
    float* orow = out + (size_t)b * OUT_ROW + (size_t)i * D_DIM - (size_t)i * (i - 1) / 2;
    for (int j = i + threadIdx.x; j < D_DIM; j += 256)
        orow[j - i] = bf2f(drow[j]) - rmi - rs[j] * inv_d + tm;
}

extern "C" void kernel_launch(void* const* d_in, const int* in_sizes, int n_in,
                              void* d_out, int out_size, void* d_ws, size_t ws_size,
                              hipStream_t stream) {
    const float* x = (const float*)d_in[0];
    float* out = (float*)d_out;

    char* ws = (char*)d_ws;
    unsigned short* xb = (unsigned short*)ws;                 // 41,943,040 B
    size_t off = 41943040;
    float* diag = (float*)(ws + off);           off += 81920;
    unsigned short* dcov = (unsigned short*)(ws + off); off += 26214400;  // bf16
    float* rowsum = (float*)(ws + off);         off += 81920;
    float* tot = (float*)(ws + off);            off += 256;

    cast_diag_kernel<<<dim3(B_DIM * D_DIM), 256, 0, stream>>>(x, xb, diag, rowsum, tot);
    gemm_dcov_kernel<<<dim3(480), 256, 0, stream>>>(xb, diag, dcov, rowsum, tot);
    output_kernel<<<dim3(B_DIM * D_DIM), 256, 0, stream>>>(dcov, rowsum, tot, out);
}